// Round 2
// baseline (248.134 us; speedup 1.0000x reference)
//
#include <hip/hip_runtime.h>
#include <math.h>

#define NB 8      // NUM_BATCHES
#define C  256    // channels
#define CR 64     // C / r

// ---------------------------------------------------------------------------
// Kernel 1: per-batch sums + counts.
// One wave (64 lanes) per row-iteration: lane l loads float4 covering
// channels 4l..4l+3 (1 KB contiguous, coalesced). bid is WAVE-UNIFORM
// (whole wave works one row) -> readfirstlane + switch gives compile-time
// accumulator indices: acc[8] float4 stays in VGPRs (rule #20), zero LDS
// traffic in the hot loop. Wave results land in LDS once at the end,
// block-reduced, then one atomicAdd per element.
// ---------------------------------------------------------------------------
__global__ __launch_bounds__(256) void pool_kernel(
    const float* __restrict__ x,      // [N, 256]
    const int*   __restrict__ bids,   // [N]
    float*       __restrict__ gsums,  // [8][256] (pre-zeroed)
    float*       __restrict__ gcnts,  // [8]      (pre-zeroed)
    int N)
{
    __shared__ float lsum[4][NB][C];   // 32 KB
    __shared__ float lcnt[4][NB];

    const int tid  = threadIdx.x;
    const int wid  = tid >> 6;
    const int lane = tid & 63;

    float4 acc[NB];
    float  cnt[NB];
    #pragma unroll
    for (int b = 0; b < NB; ++b) {
        acc[b] = make_float4(0.f, 0.f, 0.f, 0.f);
        cnt[b] = 0.f;
    }

    const int waves_total = gridDim.x * 4;

    for (int row = blockIdx.x * 4 + wid; row < N; row += waves_total) {
        const float4 v = ((const float4*)(x + (size_t)row * C))[lane];
        const int b = __builtin_amdgcn_readfirstlane(bids[row]);
#define ACC_CASE(B) case B: \
            acc[B].x += v.x; acc[B].y += v.y; acc[B].z += v.z; acc[B].w += v.w; \
            cnt[B] += 1.f; break;
        switch (b) {
            ACC_CASE(0) ACC_CASE(1) ACC_CASE(2) ACC_CASE(3)
            ACC_CASE(4) ACC_CASE(5) ACC_CASE(6) ACC_CASE(7)
        }
#undef ACC_CASE
    }

    // one float4 LDS write per batch per lane: contiguous, conflict-free
    #pragma unroll
    for (int b = 0; b < NB; ++b)
        ((float4*)&lsum[wid][b][0])[lane] = acc[b];
    if (lane == 0) {
        #pragma unroll
        for (int b = 0; b < NB; ++b) lcnt[wid][b] = cnt[b];
    }
    __syncthreads();

    for (int i = tid; i < NB * C; i += 256) {
        float s = lsum[0][0][i] + lsum[1][0][i] + lsum[2][0][i] + lsum[3][0][i];
        atomicAdd(&gsums[i], s);
    }
    if (tid < NB) {
        float s = lcnt[0][tid] + lcnt[1][tid] + lcnt[2][tid] + lcnt[3][tid];
        atomicAdd(&gcnts[tid], s);
    }
}

// ---------------------------------------------------------------------------
// Kernel 2: tiny MLP. pooled = sums/max(cnt,1); h = relu(pooled@W1+b1);
// y = sigmoid(h@W2+b2). One block, 256 threads. ~0.5 MFLOP total.
// ---------------------------------------------------------------------------
__global__ __launch_bounds__(256) void mlp_kernel(
    const float* __restrict__ gsums,  // [8][256]
    const float* __restrict__ gcnts,  // [8]
    const float* __restrict__ W1,     // [256][64]
    const float* __restrict__ b1,     // [64]
    const float* __restrict__ W2,     // [64][256]
    const float* __restrict__ b2,     // [256]
    float*       __restrict__ y)      // [8][256] out
{
    __shared__ float pooled[NB][C];
    __shared__ float h[NB][CR];
    const int tid = threadIdx.x;

    for (int i = tid; i < NB * C; i += 256) {
        const float cnt = gcnts[i >> 8];                  // i / 256 = batch
        (&pooled[0][0])[i] = gsums[i] / fmaxf(cnt, 1.f);
    }
    __syncthreads();

    // h: 8*64 = 512 outputs, 2 per thread
    for (int o = tid; o < NB * CR; o += 256) {
        const int b = o >> 6, j = o & 63;
        float acc = b1[j];
        #pragma unroll 4
        for (int k = 0; k < C; ++k) acc = fmaf(pooled[b][k], W1[k * CR + j], acc);
        (&h[0][0])[o] = fmaxf(acc, 0.f);
    }
    __syncthreads();

    // y: 8*256 = 2048 outputs, 8 per thread
    for (int o = tid; o < NB * C; o += 256) {
        const int b = o >> 8, j = o & 255;
        float acc = b2[j];
        #pragma unroll
        for (int k = 0; k < CR; ++k) acc = fmaf(h[b][k], W2[k * C + j], acc);
        y[o] = 1.f / (1.f + __expf(-acc));
    }
}

// ---------------------------------------------------------------------------
// Kernel 3: out[row, :] = y[bids[row], :] * x[row, :].
// One wave per row, float4 per lane; y (8 KB) cached in LDS.
// ---------------------------------------------------------------------------
__global__ __launch_bounds__(256) void scale_kernel(
    const float* __restrict__ x,     // [N, 256]
    const int*   __restrict__ bids,  // [N]
    const float* __restrict__ y,     // [8][256]
    float*       __restrict__ out,   // [N, 256]
    int N)
{
    __shared__ float ly[NB][C];      // 8 KB
    const int tid = threadIdx.x;
    for (int i = tid; i < NB * C; i += 256) (&ly[0][0])[i] = y[i];
    __syncthreads();

    const int wid  = tid >> 6;
    const int lane = tid & 63;
    const int waves_total = gridDim.x * 4;

    for (int row = blockIdx.x * 4 + wid; row < N; row += waves_total) {
        const int bid = bids[row];
        float4 v = ((const float4*)(x + (size_t)row * C))[lane];
        const float4 g = ((const float4*)&ly[bid][0])[lane];
        v.x *= g.x; v.y *= g.y; v.z *= g.z; v.w *= g.w;
        ((float4*)(out + (size_t)row * C))[lane] = v;
    }
}

extern "C" void kernel_launch(void* const* d_in, const int* in_sizes, int n_in,
                              void* d_out, int out_size, void* d_ws, size_t ws_size,
                              hipStream_t stream)
{
    const float* x    = (const float*)d_in[0];
    const int*   bids = (const int*)  d_in[1];
    const float* W1   = (const float*)d_in[2];
    const float* b1   = (const float*)d_in[3];
    const float* W2   = (const float*)d_in[4];
    const float* b2   = (const float*)d_in[5];
    float* out = (float*)d_out;

    const int N = in_sizes[1];           // 262144

    // workspace layout (floats): sums[2048] | cnts[8] | pad[8] | y[2048]
    float* gsums = (float*)d_ws;
    float* gcnts = gsums + NB * C;
    float* gy    = gcnts + 16;           // 16-float aligned

    // zero the accumulators (sums + counts) every call — ws is NOT re-poisoned
    hipMemsetAsync(d_ws, 0, (NB * C + NB) * sizeof(float), stream);

    pool_kernel<<<1024, 256, 0, stream>>>(x, bids, gsums, gcnts, N);
    mlp_kernel<<<1, 256, 0, stream>>>(gsums, gcnts, W1, b1, W2, b2, gy);
    scale_kernel<<<2048, 256, 0, stream>>>(x, bids, gy, out, N);
}

// Round 3
// 166.743 us; speedup vs baseline: 1.4881x; 1.4881x over previous
//
#include <hip/hip_runtime.h>
#include <math.h>

#define NB 8      // NUM_BATCHES
#define C  256    // channels
#define CR 64     // C / r

#define POOL_BLOCKS  512
#define SCALE_BLOCKS 2048

typedef float vf4 __attribute__((ext_vector_type(4)));

// ---------------------------------------------------------------------------
// Kernel 1: per-batch partial sums + counts. One wave per 4-row group
// (4 KB contiguous streaming). bid is wave-uniform -> scalar compare gives a
// 0/1 mask; accumulate is branch-free predicated FMA into vf4 acc[8] (pure
// VGPRs, ~32 fma/row ~= 7 us chip-wide). No LDS and no branches in the hot
// loop. Block-reduces 4 wave copies through LDS once at the end and writes
// per-block partials (no atomics, no memset needed).
// ---------------------------------------------------------------------------
__global__ __launch_bounds__(256) void pool_kernel(
    const float* __restrict__ x,         // [N, 256]
    const int*   __restrict__ bids,      // [N]
    float*       __restrict__ partials,  // [POOL_BLOCKS][2048]
    float*       __restrict__ cpart,     // [POOL_BLOCKS][8]
    int N)
{
    __shared__ float lsum[4][NB][C];   // 32 KB
    __shared__ float lcnt[4][NB];

    const int tid  = threadIdx.x;
    const int wid  = tid >> 6;
    const int lane = tid & 63;

    vf4   acc[NB];
    float cnt[NB];
    #pragma unroll
    for (int b = 0; b < NB; ++b) { acc[b] = (vf4){0.f,0.f,0.f,0.f}; cnt[b] = 0.f; }

    const int gwave   = blockIdx.x * 4 + wid;
    const int totw    = POOL_BLOCKS * 4;
    const int ngroups = N >> 2;

    for (int g = gwave; g < ngroups; g += totw) {
        const size_t r0 = (size_t)g * 4;
        const int b0 = __builtin_amdgcn_readfirstlane(bids[r0 + 0]);
        const int b1 = __builtin_amdgcn_readfirstlane(bids[r0 + 1]);
        const int b2 = __builtin_amdgcn_readfirstlane(bids[r0 + 2]);
        const int b3 = __builtin_amdgcn_readfirstlane(bids[r0 + 3]);
        const vf4 v0 = __builtin_nontemporal_load(((const vf4*)(x + (r0 + 0) * C)) + lane);
        const vf4 v1 = __builtin_nontemporal_load(((const vf4*)(x + (r0 + 1) * C)) + lane);
        const vf4 v2 = __builtin_nontemporal_load(((const vf4*)(x + (r0 + 2) * C)) + lane);
        const vf4 v3 = __builtin_nontemporal_load(((const vf4*)(x + (r0 + 3) * C)) + lane);
        #pragma unroll
        for (int b = 0; b < NB; ++b) {
            const float m0 = (b0 == b) ? 1.f : 0.f;
            const float m1 = (b1 == b) ? 1.f : 0.f;
            const float m2 = (b2 == b) ? 1.f : 0.f;
            const float m3 = (b3 == b) ? 1.f : 0.f;
            acc[b] += v0 * m0;
            acc[b] += v1 * m1;
            acc[b] += v2 * m2;
            acc[b] += v3 * m3;
            cnt[b] += m0 + m1 + m2 + m3;
        }
    }
    // leftover rows if N % 4 != 0 (none at N=262144) — wave 0 handles them
    if (gwave == 0) {
        for (int row = ngroups * 4; row < N; ++row) {
            const int bb = __builtin_amdgcn_readfirstlane(bids[row]);
            const vf4 v = ((const vf4*)(x + (size_t)row * C))[lane];
            #pragma unroll
            for (int b = 0; b < NB; ++b) {
                const float m = (bb == b) ? 1.f : 0.f;
                acc[b] += v * m;
                cnt[b] += m;
            }
        }
    }

    // one conflict-free b128 LDS write per batch per lane
    #pragma unroll
    for (int b = 0; b < NB; ++b)
        ((vf4*)&lsum[wid][b][0])[lane] = acc[b];
    if (lane == 0) {
        #pragma unroll
        for (int b = 0; b < NB; ++b) lcnt[wid][b] = cnt[b];
    }
    __syncthreads();

    float* pout = partials + (size_t)blockIdx.x * (NB * C);
    for (int i = tid; i < NB * C; i += 256)
        pout[i] = lsum[0][0][i] + lsum[1][0][i] + lsum[2][0][i] + lsum[3][0][i];
    if (tid < NB)
        cpart[blockIdx.x * NB + tid] =
            lcnt[0][tid] + lcnt[1][tid] + lcnt[2][tid] + lcnt[3][tid];
}

// ---------------------------------------------------------------------------
// Kernel 2: tree-reduce the per-block partials. 64 blocks: blockIdx = jp*8+jo;
// block sums 64 partial rows over its 256-col chunk (coalesced 1 KB reads).
// jo==0 blocks also reduce the count partials.
// ---------------------------------------------------------------------------
__global__ __launch_bounds__(256) void reduce_kernel(
    const float* __restrict__ partials,  // [POOL_BLOCKS][2048]
    const float* __restrict__ cpart,     // [POOL_BLOCKS][8]
    float*       __restrict__ partial2,  // [8][2048]
    float*       __restrict__ c2)        // [8][8]
{
    const int jo  = blockIdx.x & 7;   // column chunk
    const int jp  = blockIdx.x >> 3;  // partial-row chunk (64 rows each)
    const int col = jo * 256 + threadIdx.x;
    const int PR  = POOL_BLOCKS / 8;  // 64 rows per jp

    float s = 0.f;
    #pragma unroll 8
    for (int p = 0; p < PR; ++p)
        s += partials[(size_t)(jp * PR + p) * (NB * C) + col];
    partial2[jp * (NB * C) + col] = s;

    if (jo == 0 && threadIdx.x < NB) {
        float c = 0.f;
        for (int p = 0; p < PR; ++p)
            c += cpart[(jp * PR + p) * NB + threadIdx.x];
        c2[jp * NB + threadIdx.x] = c;
    }
}

// ---------------------------------------------------------------------------
// Kernel 3: final reduce + tiny MLP. pooled = sums/max(cnt,1);
// h = relu(pooled@W1+b1); y = sigmoid(h@W2+b2). One block, 256 threads.
// ---------------------------------------------------------------------------
__global__ __launch_bounds__(256) void mlp_kernel(
    const float* __restrict__ partial2,  // [8][2048]
    const float* __restrict__ c2,        // [8][8]
    const float* __restrict__ W1,        // [256][64]
    const float* __restrict__ b1,        // [64]
    const float* __restrict__ W2,        // [64][256]
    const float* __restrict__ b2,        // [256]
    float*       __restrict__ y)         // [8][256] out
{
    __shared__ float pooled[NB][C];
    __shared__ float h[NB][CR];
    __shared__ float cnts[NB];
    const int tid = threadIdx.x;

    if (tid < NB) {
        float c = 0.f;
        #pragma unroll
        for (int j = 0; j < 8; ++j) c += c2[j * NB + tid];
        cnts[tid] = fmaxf(c, 1.f);
    }
    __syncthreads();

    for (int i = tid; i < NB * C; i += 256) {
        float s = 0.f;
        #pragma unroll
        for (int j = 0; j < 8; ++j) s += partial2[j * (NB * C) + i];
        (&pooled[0][0])[i] = s / cnts[i >> 8];
    }
    __syncthreads();

    // h: 8*64 = 512 outputs, 2 per thread
    for (int o = tid; o < NB * CR; o += 256) {
        const int b = o >> 6, j = o & 63;
        float acc = b1[j];
        #pragma unroll 4
        for (int k = 0; k < C; ++k) acc = fmaf(pooled[b][k], W1[k * CR + j], acc);
        (&h[0][0])[o] = fmaxf(acc, 0.f);
    }
    __syncthreads();

    // y: 8*256 = 2048 outputs, 8 per thread
    for (int o = tid; o < NB * C; o += 256) {
        const int b = o >> 8, j = o & 255;
        float acc = b2[j];
        #pragma unroll
        for (int k = 0; k < CR; ++k) acc = fmaf(h[b][k], W2[k * C + j], acc);
        y[o] = 1.f / (1.f + __expf(-acc));
    }
}

// ---------------------------------------------------------------------------
// Kernel 4: out[row,:] = y[bids[row],:] * x[row,:]. One wave per 4-row group
// (4 KB contiguous read + 4 KB write per iteration), y cached in LDS
// (uniform bid -> conflict-free b128 reads), nontemporal streaming hints.
// ---------------------------------------------------------------------------
__global__ __launch_bounds__(256) void scale_kernel(
    const float* __restrict__ x,     // [N, 256]
    const int*   __restrict__ bids,  // [N]
    const float* __restrict__ y,     // [8][256]
    float*       __restrict__ out,   // [N, 256]
    int N)
{
    __shared__ float ly[NB][C];      // 8 KB
    const int tid = threadIdx.x;
    for (int i = tid; i < NB * C; i += 256) (&ly[0][0])[i] = y[i];
    __syncthreads();

    const int wid  = tid >> 6;
    const int lane = tid & 63;
    const int gwave   = blockIdx.x * 4 + wid;
    const int totw    = SCALE_BLOCKS * 4;
    const int ngroups = N >> 2;

    for (int g = gwave; g < ngroups; g += totw) {
        const size_t r0 = (size_t)g * 4;
        const int b0 = __builtin_amdgcn_readfirstlane(bids[r0 + 0]);
        const int b1 = __builtin_amdgcn_readfirstlane(bids[r0 + 1]);
        const int b2 = __builtin_amdgcn_readfirstlane(bids[r0 + 2]);
        const int b3 = __builtin_amdgcn_readfirstlane(bids[r0 + 3]);
        const vf4 v0 = __builtin_nontemporal_load(((const vf4*)(x + (r0 + 0) * C)) + lane);
        const vf4 v1 = __builtin_nontemporal_load(((const vf4*)(x + (r0 + 1) * C)) + lane);
        const vf4 v2 = __builtin_nontemporal_load(((const vf4*)(x + (r0 + 2) * C)) + lane);
        const vf4 v3 = __builtin_nontemporal_load(((const vf4*)(x + (r0 + 3) * C)) + lane);
        const vf4 g0 = ((const vf4*)&ly[b0][0])[lane];
        const vf4 g1 = ((const vf4*)&ly[b1][0])[lane];
        const vf4 g2 = ((const vf4*)&ly[b2][0])[lane];
        const vf4 g3 = ((const vf4*)&ly[b3][0])[lane];
        __builtin_nontemporal_store(v0 * g0, ((vf4*)(out + (r0 + 0) * C)) + lane);
        __builtin_nontemporal_store(v1 * g1, ((vf4*)(out + (r0 + 1) * C)) + lane);
        __builtin_nontemporal_store(v2 * g2, ((vf4*)(out + (r0 + 2) * C)) + lane);
        __builtin_nontemporal_store(v3 * g3, ((vf4*)(out + (r0 + 3) * C)) + lane);
    }
    if (gwave == 0) {
        for (int row = ngroups * 4; row < N; ++row) {
            const int bb = __builtin_amdgcn_readfirstlane(bids[row]);
            const vf4 v  = ((const vf4*)(x + (size_t)row * C))[lane];
            const vf4 gg = ((const vf4*)&ly[bb][0])[lane];
            ((vf4*)(out + (size_t)row * C))[lane] = v * gg;
        }
    }
}

extern "C" void kernel_launch(void* const* d_in, const int* in_sizes, int n_in,
                              void* d_out, int out_size, void* d_ws, size_t ws_size,
                              hipStream_t stream)
{
    const float* x    = (const float*)d_in[0];
    const int*   bids = (const int*)  d_in[1];
    const float* W1   = (const float*)d_in[2];
    const float* b1   = (const float*)d_in[3];
    const float* W2   = (const float*)d_in[4];
    const float* b2   = (const float*)d_in[5];
    float* out = (float*)d_out;

    const int N = in_sizes[1];           // 262144

    // ws layout (floats), all regions fully written before read each call:
    // partials[512*2048] | cpart[512*8] | partial2[8*2048] | c2[64] | gy[2048]
    float* partials = (float*)d_ws;
    float* cpart    = partials + POOL_BLOCKS * (NB * C);
    float* partial2 = cpart + POOL_BLOCKS * NB;
    float* c2       = partial2 + 8 * (NB * C);
    float* gy       = c2 + 64;

    pool_kernel  <<<POOL_BLOCKS, 256, 0, stream>>>(x, bids, partials, cpart, N);
    reduce_kernel<<<64, 256, 0, stream>>>(partials, cpart, partial2, c2);
    mlp_kernel   <<<1, 256, 0, stream>>>(partial2, c2, W1, b1, W2, b2, gy);
    scale_kernel <<<SCALE_BLOCKS, 256, 0, stream>>>(x, bids, gy, out, N);
}